// Round 9
// baseline (100.885 us; speedup 1.0000x reference)
//
#include <hip/hip_runtime.h>

#define EPS_BN 1e-5f

// B=64, N=1024, C=32, O=64, K=16. kNN/gather in the reference is dead code
// (neigh == x for all k) so mean over k is identity:
// out[b,o,n] = gelu(bn3(W3.gelu(bn2(W2.gelu(bn1(W1.x[b,n,:]))))))[o], all f32 I/O.
//
// R8 post-mortem: operand swap validated (96.96us). Remaining controllable
// cost = per-block BN fold (1024 x 40KB weight pulls + f2bf). R9: block=512
// (8 waves), grid=512 — halves fold traffic+VALU, 1 tile/wave unchanged
// (R7's regression was per-WAVE serialization, avoided here), 24 waves/CU.

typedef __attribute__((ext_vector_type(8))) short short8;   // 8 bf16 = 4 VGPRs
typedef __attribute__((ext_vector_type(4))) float f32x4;

__device__ __forceinline__ unsigned short f2bf(float f) {   // RNE f32->bf16
    unsigned int u = __float_as_uint(f);
    u += 0x7fffu + ((u >> 16) & 1u);
    return (unsigned short)(u >> 16);
}

// tanh-approx gelu, branchless, HW exp2 + rcp (R5-validated).
__device__ __forceinline__ float gelu(float v) {
    float v2 = v * v;
    float inner = fmaf(0.044715f, v2, 1.0f);
    float m = (v * 2.3022082f) * inner;
    float z = __builtin_amdgcn_exp2f(m);
    float r = __builtin_amdgcn_rcpf(z + 1.0f);
    float t = fmaf(-2.0f, r, 1.0f);
    float h = 0.5f * v;
    return fmaf(h, t, h);
}

// Block = 512 threads = 8 waves; each wave owns one 16-point m-tile.
// Grid = 512 blocks (4096 m-tiles). LDS map (40448 B):
//   [0,20480)      wlds: bf16 weights, fragment order (A-operand after swap)
//     stage1 @0:    [t:4][lane:64][j:8]
//     stage2 @2048: [t:4][kk:2][lane:64][j:8]
//     stage3 @6144: same
//   [20480,38912)  actsb: 8 waves x 16x72 bf16 act tiles [point][o]
//   [38912,40448)  scb: 192 f32 scales + 192 f32 biases
// MFMA 16x16x32 maps (measured m89/m120): A[m=lane&15][k=q*8+j],
// B[k=q*8+j][n=lane&15], C/D: col=lane&15, row=q*4+reg.
__global__ __launch_bounds__(512)
void mlp_fused(const float* __restrict__ x,
               const float* __restrict__ W1,
               const float* __restrict__ g1, const float* __restrict__ bb1,
               const float* __restrict__ m1, const float* __restrict__ v1,
               const float* __restrict__ W2,
               const float* __restrict__ g2, const float* __restrict__ bb2,
               const float* __restrict__ m2, const float* __restrict__ v2,
               const float* __restrict__ W3,
               const float* __restrict__ g3, const float* __restrict__ bb3,
               const float* __restrict__ m3, const float* __restrict__ v3,
               float* __restrict__ out)
{
    __shared__ uint4 smem4[2528];                                   // 40448 B
    unsigned short* wlds = (unsigned short*)smem4;                  // 20480 B
    unsigned short* actsb = (unsigned short*)((char*)smem4 + 20480);
    float* scb = (float*)((char*)smem4 + 38912);   // [0:192) scale, [192:384) bias

    const int tid = threadIdx.x;
    const int wave = tid >> 6, lane = tid & 63;
    const int q = lane >> 4, l15 = lane & 15;

    const int p0 = (blockIdx.x * 8 + wave) * 16;

    // ---- x prefetch (B-frag: point=lane&15, c-chunk=q*8..q*8+7) ----
    const float4* xp = (const float4*)(x + (size_t)(p0 + l15) * 32 + q * 8);
    float4 xa = xp[0], xb = xp[1];

    // ---- fold phase A: 192 BN scale/bias terms ----
    if (tid < 192) {
        int s = tid >> 6, o = tid & 63;
        const float* gg  = (s == 0) ? g1  : (s == 1) ? g2  : g3;
        const float* vv  = (s == 0) ? v1  : (s == 1) ? v2  : v3;
        const float* bbp = (s == 0) ? bb1 : (s == 1) ? bb2 : bb3;
        const float* mm  = (s == 0) ? m1  : (s == 1) ? m2  : m3;
        float sc = gg[o] * rsqrtf(vv[o] + EPS_BN);
        scb[tid] = sc;
        scb[192 + tid] = bbp[o] - mm[o] * sc;
    }
    __syncthreads();

    // ---- fold phase B: coalesced raw-weight load -> swizzled bf16 LDS ----
    // 4 fragment-order dests per source float4 are consecutive -> ds_write_b64.
    {
        const float4* wv = (const float4*)W1;   // 512 float4, 1/thread
        int e4 = tid;
        float4 w = wv[e4];
        int s0 = e4 << 2;
        int o = s0 >> 5, c0 = s0 & 31;
        float sc = scb[o];
        int dst = ((o >> 4) << 9) + (((((c0 >> 3) << 4) | (o & 15))) << 3) + (c0 & 7);
        unsigned short pk[4] = { f2bf(w.x * sc), f2bf(w.y * sc),
                                 f2bf(w.z * sc), f2bf(w.w * sc) };
        *(uint2*)(wlds + dst) = *(const uint2*)pk;
    }
    {
        const float4* wv = (const float4*)W2;   // 1024 float4, 2/thread
#pragma unroll
        for (int r = 0; r < 2; ++r) {
            int e4 = tid + r * 512;
            float4 w = wv[e4];
            int s0 = e4 << 2;
            int o = s0 >> 6, c0 = s0 & 63;
            float sc = scb[64 + o];
            int dst = 2048 + ((o >> 4) << 10) + ((c0 >> 5) << 9)
                    + ((((((c0 >> 3) & 3) << 4) | (o & 15))) << 3) + (c0 & 7);
            unsigned short pk[4] = { f2bf(w.x * sc), f2bf(w.y * sc),
                                     f2bf(w.z * sc), f2bf(w.w * sc) };
            *(uint2*)(wlds + dst) = *(const uint2*)pk;
        }
    }
    {
        const float4* wv = (const float4*)W3;   // 1024 float4, 2/thread
#pragma unroll
        for (int r = 0; r < 2; ++r) {
            int e4 = tid + r * 512;
            float4 w = wv[e4];
            int s0 = e4 << 2;
            int o = s0 >> 6, c0 = s0 & 63;
            float sc = scb[128 + o];
            int dst = 6144 + ((o >> 4) << 10) + ((c0 >> 5) << 9)
                    + ((((((c0 >> 3) & 3) << 4) | (o & 15))) << 3) + (c0 & 7);
            unsigned short pk[4] = { f2bf(w.x * sc), f2bf(w.y * sc),
                                     f2bf(w.z * sc), f2bf(w.w * sc) };
            *(uint2*)(wlds + dst) = *(const uint2*)pk;
        }
    }
    __syncthreads();   // weights + scb staged

    // ---- stage-1 B-frag (acts side) from prefetched x ----
    short8 a1;
    a1[0] = (short)f2bf(xa.x); a1[1] = (short)f2bf(xa.y);
    a1[2] = (short)f2bf(xa.z); a1[3] = (short)f2bf(xa.w);
    a1[4] = (short)f2bf(xb.x); a1[5] = (short)f2bf(xb.y);
    a1[6] = (short)f2bf(xb.z); a1[7] = (short)f2bf(xb.w);

    unsigned short* aw = actsb + wave * (16 * 72);

    // ---- stage 1: 32 -> 64.  D[row=o=q*4+r][col=point=l15] ----
#pragma unroll
    for (int t = 0; t < 4; ++t) {
        f32x4 acc = *(const f32x4*)(scb + 192 + 0 * 64 + t * 16 + q * 4);  // broadcast
        short8 wf = *(const short8*)(wlds + ((t * 64 + lane) << 3));
        acc = __builtin_amdgcn_mfma_f32_16x16x32_bf16(wf, a1, acc, 0, 0, 0);
        unsigned short pk[4] = { f2bf(gelu(acc[0])), f2bf(gelu(acc[1])),
                                 f2bf(gelu(acc[2])), f2bf(gelu(acc[3])) };
        *(uint2*)(aw + l15 * 72 + t * 16 + q * 4) = *(const uint2*)pk;  // [point][o]
    }
    __threadfence_block();

    // ---- stage 2: 64 -> 64 ----
    short8 a20 = *(const short8*)(aw + l15 * 72 + q * 8);        // acts[point][c0..]
    short8 a21 = *(const short8*)(aw + l15 * 72 + 32 + q * 8);
#pragma unroll
    for (int t = 0; t < 4; ++t) {
        f32x4 acc = *(const f32x4*)(scb + 192 + 1 * 64 + t * 16 + q * 4);
        short8 w0 = *(const short8*)(wlds + 2048 + ((t * 2 + 0) * 64 + lane) * 8);
        short8 w1 = *(const short8*)(wlds + 2048 + ((t * 2 + 1) * 64 + lane) * 8);
        acc = __builtin_amdgcn_mfma_f32_16x16x32_bf16(w0, a20, acc, 0, 0, 0);
        acc = __builtin_amdgcn_mfma_f32_16x16x32_bf16(w1, a21, acc, 0, 0, 0);
        unsigned short pk[4] = { f2bf(gelu(acc[0])), f2bf(gelu(acc[1])),
                                 f2bf(gelu(acc[2])), f2bf(gelu(acc[3])) };
        *(uint2*)(aw + l15 * 72 + t * 16 + q * 4) = *(const uint2*)pk;
    }
    __threadfence_block();

    // ---- stage 3: 64 -> 64, direct stores (quad = 64B run of out[o][n]) ----
    short8 a30 = *(const short8*)(aw + l15 * 72 + q * 8);
    short8 a31 = *(const short8*)(aw + l15 * 72 + 32 + q * 8);
    const int bb = p0 >> 10;
    const int n0 = p0 & 1023;
    float* outb = out + (size_t)bb * 65536 + n0 + l15;
#pragma unroll
    for (int t = 0; t < 4; ++t) {
        f32x4 acc = *(const f32x4*)(scb + 192 + 2 * 64 + t * 16 + q * 4);
        short8 w0 = *(const short8*)(wlds + 6144 + ((t * 2 + 0) * 64 + lane) * 8);
        short8 w1 = *(const short8*)(wlds + 6144 + ((t * 2 + 1) * 64 + lane) * 8);
        acc = __builtin_amdgcn_mfma_f32_16x16x32_bf16(w0, a30, acc, 0, 0, 0);
        acc = __builtin_amdgcn_mfma_f32_16x16x32_bf16(w1, a31, acc, 0, 0, 0);
#pragma unroll
        for (int r = 0; r < 4; ++r)
            outb[(size_t)(t * 16 + q * 4 + r) * 1024] = gelu(acc[r]);
    }
}

extern "C" void kernel_launch(void* const* d_in, const int* in_sizes, int n_in,
                              void* d_out, int out_size, void* d_ws, size_t ws_size,
                              hipStream_t stream) {
    const float* x  = (const float*)d_in[0];
    const float* W1 = (const float*)d_in[1];
    const float* g1 = (const float*)d_in[2];
    const float* b1 = (const float*)d_in[3];
    const float* m1 = (const float*)d_in[4];
    const float* v1 = (const float*)d_in[5];
    const float* W2 = (const float*)d_in[6];
    const float* g2 = (const float*)d_in[7];
    const float* b2 = (const float*)d_in[8];
    const float* m2 = (const float*)d_in[9];
    const float* v2 = (const float*)d_in[10];
    const float* W3 = (const float*)d_in[11];
    const float* g3 = (const float*)d_in[12];
    const float* b3 = (const float*)d_in[13];
    const float* m3 = (const float*)d_in[14];
    const float* v3 = (const float*)d_in[15];
    float* out = (float*)d_out;

    mlp_fused<<<512, 512, 0, stream>>>(x, W1, g1, b1, m1, v1,
                                       W2, g2, b2, m2, v2,
                                       W3, g3, b3, m3, v3, out);
}

// Round 10
// 96.836 us; speedup vs baseline: 1.0418x; 1.0418x over previous
//
#include <hip/hip_runtime.h>

#define EPS_BN 1e-5f

// B=64, N=1024, C=32, O=64, K=16. kNN/gather in the reference is dead code
// (neigh == x for all k) so mean over k is identity:
// out[b,o,n] = gelu(bn3(W3.gelu(bn2(W2.gelu(bn1(W1.x[b,n,:]))))))[o], all f32 I/O.
//
// R9 post-mortem: block=512 regressed (2 blocks/CU + 8-wave barrier); fold
// amortization is a dead end (R7, R9 both regressed). R10: exact R8 structure
// (grid 1024 x block 256, operand-swapped MFMA, 96.96us) + weight float4 loads
// hoisted to registers BEFORE the scb barrier so L2 latency overlaps it.

typedef __attribute__((ext_vector_type(8))) short short8;   // 8 bf16 = 4 VGPRs
typedef __attribute__((ext_vector_type(4))) float f32x4;

__device__ __forceinline__ unsigned short f2bf(float f) {   // RNE f32->bf16
    unsigned int u = __float_as_uint(f);
    u += 0x7fffu + ((u >> 16) & 1u);
    return (unsigned short)(u >> 16);
}

// tanh-approx gelu, branchless, HW exp2 + rcp (R5-validated).
__device__ __forceinline__ float gelu(float v) {
    float v2 = v * v;
    float inner = fmaf(0.044715f, v2, 1.0f);
    float m = (v * 2.3022082f) * inner;
    float z = __builtin_amdgcn_exp2f(m);
    float r = __builtin_amdgcn_rcpf(z + 1.0f);
    float t = fmaf(-2.0f, r, 1.0f);
    float h = 0.5f * v;
    return fmaf(h, t, h);
}

// Block = 256 threads = 4 waves; each wave owns one 16-point m-tile.
// Grid = 1024 blocks. LDS map (31232 B):
//   [0,20480)      wlds: bf16 weights, fragment order (A-operand after swap)
//     stage1 @0:    [t:4][lane:64][j:8]
//     stage2 @2048: [t:4][kk:2][lane:64][j:8]
//     stage3 @6144: same
//   [20480,29696)  actsb: 4 waves x 16x72 bf16 act tiles [point][o]
//   [29696,31232)  scb: 192 f32 scales + 192 f32 biases
// MFMA 16x16x32 maps (measured m89/m120): A[m=lane&15][k=q*8+j],
// B[k=q*8+j][n=lane&15], C/D: col=lane&15, row=q*4+reg.
__global__ __launch_bounds__(256, 4)
void mlp_fused(const float* __restrict__ x,
               const float* __restrict__ W1,
               const float* __restrict__ g1, const float* __restrict__ bb1,
               const float* __restrict__ m1, const float* __restrict__ v1,
               const float* __restrict__ W2,
               const float* __restrict__ g2, const float* __restrict__ bb2,
               const float* __restrict__ m2, const float* __restrict__ v2,
               const float* __restrict__ W3,
               const float* __restrict__ g3, const float* __restrict__ bb3,
               const float* __restrict__ m3, const float* __restrict__ v3,
               float* __restrict__ out)
{
    __shared__ uint4 smem4[1952];                                   // 31232 B
    unsigned short* wlds = (unsigned short*)smem4;                  // 20480 B
    unsigned short* actsb = (unsigned short*)((char*)smem4 + 20480);
    float* scb = (float*)((char*)smem4 + 29696);   // [0:192) scale, [192:384) bias

    const int tid = threadIdx.x;
    const int wave = tid >> 6, lane = tid & 63;
    const int q = lane >> 4, l15 = lane & 15;

    const int p0 = (blockIdx.x * 4 + wave) * 16;

    // ---- x prefetch (B-frag: point=lane&15, c-chunk=q*8..q*8+7) ----
    const float4* xp = (const float4*)(x + (size_t)(p0 + l15) * 32 + q * 8);
    float4 xa = xp[0], xb = xp[1];

    // ---- weight prefetch to registers (latency overlaps scb phase+barrier) ----
    float4 w1r[2], w2r[4], w3r[4];
#pragma unroll
    for (int r = 0; r < 2; ++r) w1r[r] = ((const float4*)W1)[tid + r * 256];
#pragma unroll
    for (int r = 0; r < 4; ++r) w2r[r] = ((const float4*)W2)[tid + r * 256];
#pragma unroll
    for (int r = 0; r < 4; ++r) w3r[r] = ((const float4*)W3)[tid + r * 256];

    // ---- fold phase A: 192 BN scale/bias terms ----
    if (tid < 192) {
        int s = tid >> 6, o = tid & 63;
        const float* gg  = (s == 0) ? g1  : (s == 1) ? g2  : g3;
        const float* vv  = (s == 0) ? v1  : (s == 1) ? v2  : v3;
        const float* bbp = (s == 0) ? bb1 : (s == 1) ? bb2 : bb3;
        const float* mm  = (s == 0) ? m1  : (s == 1) ? m2  : m3;
        float sc = gg[o] * rsqrtf(vv[o] + EPS_BN);
        scb[tid] = sc;
        scb[192 + tid] = bbp[o] - mm[o] * sc;
    }
    __syncthreads();

    // ---- fold phase B: scale prefetched weights -> swizzled bf16 LDS ----
    // 4 fragment-order dests per source float4 are consecutive -> ds_write_b64.
#pragma unroll
    for (int r = 0; r < 2; ++r) {
        int e4 = tid + r * 256;
        float4 w = w1r[r];
        int s0 = e4 << 2;
        int o = s0 >> 5, c0 = s0 & 31;
        float sc = scb[o];
        int dst = ((o >> 4) << 9) + (((((c0 >> 3) << 4) | (o & 15))) << 3) + (c0 & 7);
        unsigned short pk[4] = { f2bf(w.x * sc), f2bf(w.y * sc),
                                 f2bf(w.z * sc), f2bf(w.w * sc) };
        *(uint2*)(wlds + dst) = *(const uint2*)pk;
    }
#pragma unroll
    for (int r = 0; r < 4; ++r) {
        int e4 = tid + r * 256;
        float4 w = w2r[r];
        int s0 = e4 << 2;
        int o = s0 >> 6, c0 = s0 & 63;
        float sc = scb[64 + o];
        int dst = 2048 + ((o >> 4) << 10) + ((c0 >> 5) << 9)
                + ((((((c0 >> 3) & 3) << 4) | (o & 15))) << 3) + (c0 & 7);
        unsigned short pk[4] = { f2bf(w.x * sc), f2bf(w.y * sc),
                                 f2bf(w.z * sc), f2bf(w.w * sc) };
        *(uint2*)(wlds + dst) = *(const uint2*)pk;
    }
#pragma unroll
    for (int r = 0; r < 4; ++r) {
        int e4 = tid + r * 256;
        float4 w = w3r[r];
        int s0 = e4 << 2;
        int o = s0 >> 6, c0 = s0 & 63;
        float sc = scb[128 + o];
        int dst = 6144 + ((o >> 4) << 10) + ((c0 >> 5) << 9)
                + ((((((c0 >> 3) & 3) << 4) | (o & 15))) << 3) + (c0 & 7);
        unsigned short pk[4] = { f2bf(w.x * sc), f2bf(w.y * sc),
                                 f2bf(w.z * sc), f2bf(w.w * sc) };
        *(uint2*)(wlds + dst) = *(const uint2*)pk;
    }
    __syncthreads();   // weights + scb staged

    // ---- stage-1 B-frag (acts side) from prefetched x ----
    short8 a1;
    a1[0] = (short)f2bf(xa.x); a1[1] = (short)f2bf(xa.y);
    a1[2] = (short)f2bf(xa.z); a1[3] = (short)f2bf(xa.w);
    a1[4] = (short)f2bf(xb.x); a1[5] = (short)f2bf(xb.y);
    a1[6] = (short)f2bf(xb.z); a1[7] = (short)f2bf(xb.w);

    unsigned short* aw = actsb + wave * (16 * 72);

    // ---- stage 1: 32 -> 64.  D[row=o=q*4+r][col=point=l15] ----
#pragma unroll
    for (int t = 0; t < 4; ++t) {
        f32x4 acc = *(const f32x4*)(scb + 192 + 0 * 64 + t * 16 + q * 4);  // broadcast
        short8 wf = *(const short8*)(wlds + ((t * 64 + lane) << 3));
        acc = __builtin_amdgcn_mfma_f32_16x16x32_bf16(wf, a1, acc, 0, 0, 0);
        unsigned short pk[4] = { f2bf(gelu(acc[0])), f2bf(gelu(acc[1])),
                                 f2bf(gelu(acc[2])), f2bf(gelu(acc[3])) };
        *(uint2*)(aw + l15 * 72 + t * 16 + q * 4) = *(const uint2*)pk;  // [point][o]
    }
    __threadfence_block();

    // ---- stage 2: 64 -> 64 ----
    short8 a20 = *(const short8*)(aw + l15 * 72 + q * 8);        // acts[point][c0..]
    short8 a21 = *(const short8*)(aw + l15 * 72 + 32 + q * 8);
#pragma unroll
    for (int t = 0; t < 4; ++t) {
        f32x4 acc = *(const f32x4*)(scb + 192 + 1 * 64 + t * 16 + q * 4);
        short8 w0 = *(const short8*)(wlds + 2048 + ((t * 2 + 0) * 64 + lane) * 8);
        short8 w1 = *(const short8*)(wlds + 2048 + ((t * 2 + 1) * 64 + lane) * 8);
        acc = __builtin_amdgcn_mfma_f32_16x16x32_bf16(w0, a20, acc, 0, 0, 0);
        acc = __builtin_amdgcn_mfma_f32_16x16x32_bf16(w1, a21, acc, 0, 0, 0);
        unsigned short pk[4] = { f2bf(gelu(acc[0])), f2bf(gelu(acc[1])),
                                 f2bf(gelu(acc[2])), f2bf(gelu(acc[3])) };
        *(uint2*)(aw + l15 * 72 + t * 16 + q * 4) = *(const uint2*)pk;
    }
    __threadfence_block();

    // ---- stage 3: 64 -> 64, direct stores (quad = 64B run of out[o][n]) ----
    short8 a30 = *(const short8*)(aw + l15 * 72 + q * 8);
    short8 a31 = *(const short8*)(aw + l15 * 72 + 32 + q * 8);
    const int bb = p0 >> 10;
    const int n0 = p0 & 1023;
    float* outb = out + (size_t)bb * 65536 + n0 + l15;
#pragma unroll
    for (int t = 0; t < 4; ++t) {
        f32x4 acc = *(const f32x4*)(scb + 192 + 2 * 64 + t * 16 + q * 4);
        short8 w0 = *(const short8*)(wlds + 6144 + ((t * 2 + 0) * 64 + lane) * 8);
        short8 w1 = *(const short8*)(wlds + 6144 + ((t * 2 + 1) * 64 + lane) * 8);
        acc = __builtin_amdgcn_mfma_f32_16x16x32_bf16(w0, a30, acc, 0, 0, 0);
        acc = __builtin_amdgcn_mfma_f32_16x16x32_bf16(w1, a31, acc, 0, 0, 0);
#pragma unroll
        for (int r = 0; r < 4; ++r)
            outb[(size_t)(t * 16 + q * 4 + r) * 1024] = gelu(acc[r]);
    }
}

extern "C" void kernel_launch(void* const* d_in, const int* in_sizes, int n_in,
                              void* d_out, int out_size, void* d_ws, size_t ws_size,
                              hipStream_t stream) {
    const float* x  = (const float*)d_in[0];
    const float* W1 = (const float*)d_in[1];
    const float* g1 = (const float*)d_in[2];
    const float* b1 = (const float*)d_in[3];
    const float* m1 = (const float*)d_in[4];
    const float* v1 = (const float*)d_in[5];
    const float* W2 = (const float*)d_in[6];
    const float* g2 = (const float*)d_in[7];
    const float* b2 = (const float*)d_in[8];
    const float* m2 = (const float*)d_in[9];
    const float* v2 = (const float*)d_in[10];
    const float* W3 = (const float*)d_in[11];
    const float* g3 = (const float*)d_in[12];
    const float* b3 = (const float*)d_in[13];
    const float* m3 = (const float*)d_in[14];
    const float* v3 = (const float*)d_in[15];
    float* out = (float*)d_out;

    mlp_fused<<<1024, 256, 0, stream>>>(x, W1, g1, b1, m1, v1,
                                        W2, g2, b2, m2, v2,
                                        W3, g3, b3, m3, v3, out);
}